// Round 9
// baseline (355.934 us; speedup 1.0000x reference)
//
#include <hip/hip_runtime.h>
#include <hip/hip_bf16.h>
#include <cstdint>
#include <cstddef>

// Problem constants
#define B_    2
#define S_    2048
#define HID_  2048
#define H_    32
#define HKV_  8
#define DH_   64
// SCALE * log2(e): scores scaled into exp2 domain
#define SC2_  0.1803368801111244f

typedef __bf16 bf16;
typedef bf16  bf16x2 __attribute__((ext_vector_type(2)));
typedef bf16  bf16x4 __attribute__((ext_vector_type(4)));
typedef bf16  bf16x8 __attribute__((ext_vector_type(8)));
typedef float f32x4  __attribute__((ext_vector_type(4)));
typedef float f32x16 __attribute__((ext_vector_type(16)));
typedef uint32_t u32x2 __attribute__((ext_vector_type(2)));

typedef __attribute__((address_space(3))) uint32_t  lds_u32_t;
typedef __attribute__((address_space(1))) const uint32_t glob_u32_t;

__device__ __forceinline__ void async16(const void* g, void* l) {
    __builtin_amdgcn_global_load_lds((glob_u32_t*)g, (lds_u32_t*)l, 16, 0, 0);
}

__device__ __forceinline__ bf16x8 cvt8(float4 a, float4 b) {
    bf16x8 r;
    r[0] = (bf16)a.x; r[1] = (bf16)a.y; r[2] = (bf16)a.z; r[3] = (bf16)a.w;
    r[4] = (bf16)b.x; r[5] = (bf16)b.y; r[6] = (bf16)b.z; r[7] = (bf16)b.w;
    return r;
}

__device__ __forceinline__ uint32_t pkbf(float a, float b) {
    bf16x2 t; t[0] = (bf16)a; t[1] = (bf16)b;
    return __builtin_bit_cast(uint32_t, t);
}
__device__ __forceinline__ bf16x8 mk8(uint32_t a, uint32_t b, uint32_t c, uint32_t d) {
    union { uint32_t u[4]; bf16x8 v; } t;
    t.u[0] = a; t.u[1] = b; t.u[2] = c; t.u[3] = d;
    return t.v;
}

// two raw barriers around compute; counted vmcnt keeps prefetch in flight
#define WAIT_N_BARRIER(N_ASM)                              \
    asm volatile(N_ASM ::: "memory");                      \
    __builtin_amdgcn_s_barrier();                          \
    __builtin_amdgcn_sched_barrier(0);

#define END_BARRIER()                                      \
    __builtin_amdgcn_sched_barrier(0);                     \
    __builtin_amdgcn_s_barrier();

// ---------------------------------------------------------------------------
// Merged fp32->bf16 convert for all 5 tensors (one launch).
// ---------------------------------------------------------------------------
__global__ __launch_bounds__(256) void cvt_all_kernel(
    const float* __restrict__ X,  const float* __restrict__ Wq,
    const float* __restrict__ Wk, const float* __restrict__ Wv,
    const float* __restrict__ Wo,
    bf16* __restrict__ Xb,  bf16* __restrict__ Wqb, bf16* __restrict__ Wkb,
    bf16* __restrict__ Wvb, bf16* __restrict__ Wob)
{
    const int i = blockIdx.x * 256 + threadIdx.x;
    const float* src; bf16* dst; int off;
    if (i < 1048576)      { src = X;  dst = Xb;  off = i; }
    else if (i < 1572864) { src = Wq; dst = Wqb; off = i - 1048576; }
    else if (i < 1703936) { src = Wk; dst = Wkb; off = i - 1572864; }
    else if (i < 1835008) { src = Wv; dst = Wvb; off = i - 1703936; }
    else                  { src = Wo; dst = Wob; off = i - 1835008; }
    float4 a = ((const float4*)src)[2 * off];
    float4 b = ((const float4*)src)[2 * off + 1];
    ((bf16x8*)dst)[off] = cvt8(a, b);
}

// ---------------------------------------------------------------------------
// Fused QKV projection GEMM. V written TRANSPOSED (b,hkv,d,s).
// Q pre-scaled by SCALE*log2e so attn scores land in exp2 domain directly.
// dbuf LDS + raw-barrier pair + counted vmcnt(8) + bijective XCD swizzle.
// ---------------------------------------------------------------------------
__global__ __launch_bounds__(256) void gemm_qkv_kernel(
    const bf16* __restrict__ A,
    const bf16* __restrict__ Wqb, const bf16* __restrict__ Wkb,
    const bf16* __restrict__ Wvb,
    const float* __restrict__ cs, const float* __restrict__ sn,
    bf16* __restrict__ Qo, bf16* __restrict__ Ko, bf16* __restrict__ Vt)
{
    __shared__ bf16 a_lds[2][128 * 64];
    __shared__ bf16 b_lds[2][128 * 64];

    const int tid  = threadIdx.x;
    const int wave = tid >> 6;
    const int lane = tid & 63;
    const int quad = lane >> 4;
    const int l16  = lane & 15;
    const int wm   = wave >> 1;
    const int wn   = wave & 1;

    // XCD-aware swizzle: 768 blocks -> 8 chunks of 96 contiguous tiles
    const int idx = blockIdx.x + 32 * blockIdx.y;
    const int swz = (idx & 7) * 96 + (idx >> 3);
    const int m0  = (swz & 31) * 128;
    const int n0  = (swz >> 5) * 128;

    f32x4 acc[4][4];
    #pragma unroll
    for (int mt = 0; mt < 4; ++mt)
        #pragma unroll
        for (int nt = 0; nt < 4; ++nt)
            acc[mt][nt] = (f32x4){0.f, 0.f, 0.f, 0.f};

    int srow[4], sgcol[4];
    const bf16* browp[4];
    #pragma unroll
    for (int i = 0; i < 4; ++i) {
        const int e = tid * 8 + i * 2048;
        srow[i] = e >> 6;
        const int chunk = (e >> 3) & 7;
        sgcol[i] = (chunk ^ (srow[i] & 7)) << 3;
        const int n = n0 + srow[i];
        browp[i] = (n < 2048) ? (Wqb + (size_t)n * HID_)
                 : (n < 2560) ? (Wkb + (size_t)(n - 2048) * HID_)
                              : (Wvb + (size_t)(n - 2560) * HID_);
    }

    // prologue: stage K-tile 0 into buffer 0 (8 loads/wave)
    #pragma unroll
    for (int i = 0; i < 4; ++i) {
        async16(A + (size_t)(m0 + srow[i]) * HID_ + sgcol[i],
                &a_lds[0][tid * 8 + i * 2048]);
        async16(browp[i] + sgcol[i],
                &b_lds[0][tid * 8 + i * 2048]);
    }

    for (int k0 = 0; k0 < HID_; k0 += 64) {
        const int cur = (k0 >> 6) & 1;
        if (k0 + 64 < HID_) {
            #pragma unroll
            for (int i = 0; i < 4; ++i) {
                async16(A + (size_t)(m0 + srow[i]) * HID_ + k0 + 64 + sgcol[i],
                        &a_lds[cur ^ 1][tid * 8 + i * 2048]);
                async16(browp[i] + k0 + 64 + sgcol[i],
                        &b_lds[cur ^ 1][tid * 8 + i * 2048]);
            }
            WAIT_N_BARRIER("s_waitcnt vmcnt(8)");   // tile k0 landed; k0+64 in flight
        } else {
            WAIT_N_BARRIER("s_waitcnt vmcnt(0)");
        }
        const bf16* al = a_lds[cur];
        const bf16* bl = b_lds[cur];
        #pragma unroll
        for (int ks = 0; ks < 2; ++ks) {
            bf16x8 af[4], bfr[4];
            #pragma unroll
            for (int mt = 0; mt < 4; ++mt) {
                const int row = wm * 64 + mt * 16 + l16;
                const int c = (ks * 4 + quad) ^ (row & 7);
                af[mt] = *(const bf16x8*)(&al[row * 64 + c * 8]);
            }
            #pragma unroll
            for (int nt = 0; nt < 4; ++nt) {
                const int row = wn * 64 + nt * 16 + l16;
                const int c = (ks * 4 + quad) ^ (row & 7);
                bfr[nt] = *(const bf16x8*)(&bl[row * 64 + c * 8]);
            }
            #pragma unroll
            for (int mt = 0; mt < 4; ++mt)
                #pragma unroll
                for (int nt = 0; nt < 4; ++nt)
                    acc[mt][nt] = __builtin_amdgcn_mfma_f32_16x16x32_bf16(
                        af[mt], bfr[nt], acc[mt][nt], 0, 0, 0);
        }
        END_BARRIER();   // all waves done reading buf[cur] before t+2 overwrites
    }

    const int nw = n0 + wn * 64;
    const int d  = l16;
    #pragma unroll
    for (int mt = 0; mt < 4; ++mt) {
        #pragma unroll
        for (int r = 0; r < 4; ++r) {
            const int m  = m0 + wm * 64 + mt * 16 + quad * 4 + r;
            const int bb = m >> 11;
            const int ss = m & (S_ - 1);
            const float v0 = acc[mt][0][r], v1 = acc[mt][1][r];
            const float v2 = acc[mt][2][r], v3 = acc[mt][3][r];
            if (nw < 2048) {
                const int h = nw >> 6;
                bf16* dp = Qo + ((size_t)(bb * H_ + h) * S_ + ss) * DH_;
                const float* cp = cs + ((size_t)bb * S_ + ss) * DH_;
                const float* sp = sn + ((size_t)bb * S_ + ss) * DH_;
                dp[ 0 + d] = (bf16)((v0 * cp[ 0 + d] - v2 * sp[ 0 + d]) * SC2_);
                dp[16 + d] = (bf16)((v1 * cp[16 + d] - v3 * sp[16 + d]) * SC2_);
                dp[32 + d] = (bf16)((v2 * cp[32 + d] + v0 * sp[32 + d]) * SC2_);
                dp[48 + d] = (bf16)((v3 * cp[48 + d] + v1 * sp[48 + d]) * SC2_);
            } else if (nw < 2560) {
                const int h = (nw - 2048) >> 6;
                bf16* dp = Ko + ((size_t)(bb * HKV_ + h) * S_ + ss) * DH_;
                const float* cp = cs + ((size_t)bb * S_ + ss) * DH_;
                const float* sp = sn + ((size_t)bb * S_ + ss) * DH_;
                dp[ 0 + d] = (bf16)(v0 * cp[ 0 + d] - v2 * sp[ 0 + d]);
                dp[16 + d] = (bf16)(v1 * cp[16 + d] - v3 * sp[16 + d]);
                dp[32 + d] = (bf16)(v2 * cp[32 + d] + v0 * sp[32 + d]);
                dp[48 + d] = (bf16)(v3 * cp[48 + d] + v1 * sp[48 + d]);
            } else {
                const int h = (nw - 2560) >> 6;
                bf16* dp = Vt + ((size_t)(bb * HKV_ + h) * DH_) * S_ + ss;
                dp[(size_t)( 0 + d) * S_] = (bf16)v0;
                dp[(size_t)(16 + d) * S_] = (bf16)v1;
                dp[(size_t)(32 + d) * S_] = (bf16)v2;
                dp[(size_t)(48 + d) * S_] = (bf16)v3;
            }
        }
    }
}

// ---------------------------------------------------------------------------
// Output projection: Y (4096 x 2048 fp32) = Ob (bf16, (b,s,h*d)) * Wob^T.
// Same raw-barrier + counted-vmcnt pipeline.
// ---------------------------------------------------------------------------
__global__ __launch_bounds__(256) void gemm_out_kernel(
    const bf16* __restrict__ A, const bf16* __restrict__ Wb,
    float* __restrict__ Y)
{
    __shared__ bf16 a_lds[2][128 * 64];
    __shared__ bf16 b_lds[2][128 * 64];

    const int tid  = threadIdx.x;
    const int wave = tid >> 6;
    const int lane = tid & 63;
    const int quad = lane >> 4;
    const int l16  = lane & 15;
    const int wm   = wave >> 1;
    const int wn   = wave & 1;

    const int idx = blockIdx.x + 32 * blockIdx.y;
    const int swz = (idx & 7) * 64 + (idx >> 3);
    const int m0  = (swz & 31) * 128;
    const int n0  = (swz >> 5) * 128;

    f32x4 acc[4][4];
    #pragma unroll
    for (int mt = 0; mt < 4; ++mt)
        #pragma unroll
        for (int nt = 0; nt < 4; ++nt)
            acc[mt][nt] = (f32x4){0.f, 0.f, 0.f, 0.f};

    int srow[4], sgcol[4];
    #pragma unroll
    for (int i = 0; i < 4; ++i) {
        const int e = tid * 8 + i * 2048;
        srow[i] = e >> 6;
        const int chunk = (e >> 3) & 7;
        sgcol[i] = (chunk ^ (srow[i] & 7)) << 3;
    }

    // prologue: stage K-tile 0 into buffer 0
    #pragma unroll
    for (int i = 0; i < 4; ++i) {
        async16(A + (size_t)(m0 + srow[i]) * HID_ + sgcol[i],
                &a_lds[0][tid * 8 + i * 2048]);
        async16(Wb + (size_t)(n0 + srow[i]) * HID_ + sgcol[i],
                &b_lds[0][tid * 8 + i * 2048]);
    }

    for (int k0 = 0; k0 < HID_; k0 += 64) {
        const int cur = (k0 >> 6) & 1;
        if (k0 + 64 < HID_) {
            #pragma unroll
            for (int i = 0; i < 4; ++i) {
                async16(A + (size_t)(m0 + srow[i]) * HID_ + k0 + 64 + sgcol[i],
                        &a_lds[cur ^ 1][tid * 8 + i * 2048]);
                async16(Wb + (size_t)(n0 + srow[i]) * HID_ + k0 + 64 + sgcol[i],
                        &b_lds[cur ^ 1][tid * 8 + i * 2048]);
            }
            WAIT_N_BARRIER("s_waitcnt vmcnt(8)");
        } else {
            WAIT_N_BARRIER("s_waitcnt vmcnt(0)");
        }
        const bf16* al = a_lds[cur];
        const bf16* bl = b_lds[cur];
        #pragma unroll
        for (int ks = 0; ks < 2; ++ks) {
            bf16x8 af[4], bfr[4];
            #pragma unroll
            for (int mt = 0; mt < 4; ++mt) {
                const int row = wm * 64 + mt * 16 + l16;
                const int c = (ks * 4 + quad) ^ (row & 7);
                af[mt] = *(const bf16x8*)(&al[row * 64 + c * 8]);
            }
            #pragma unroll
            for (int nt = 0; nt < 4; ++nt) {
                const int row = wn * 64 + nt * 16 + l16;
                const int c = (ks * 4 + quad) ^ (row & 7);
                bfr[nt] = *(const bf16x8*)(&bl[row * 64 + c * 8]);
            }
            #pragma unroll
            for (int mt = 0; mt < 4; ++mt)
                #pragma unroll
                for (int nt = 0; nt < 4; ++nt)
                    acc[mt][nt] = __builtin_amdgcn_mfma_f32_16x16x32_bf16(
                        af[mt], bfr[nt], acc[mt][nt], 0, 0, 0);
        }
        END_BARRIER();
    }

    #pragma unroll
    for (int mt = 0; mt < 4; ++mt)
        #pragma unroll
        for (int nt = 0; nt < 4; ++nt)
            #pragma unroll
            for (int r = 0; r < 4; ++r) {
                const int m = m0 + wm * 64 + mt * 16 + quad * 4 + r;
                const int n = n0 + wn * 64 + nt * 16 + l16;
                Y[(size_t)m * HID_ + n] = acc[mt][nt][r];
            }
}

// ---------------------------------------------------------------------------
// Flash attention v12 (causal, GQA), 32x32x16 MFMA — 8-WAVE BLOCKS.
// Round-8 post-mortem: occupancy is pinned at ~2 resident BLOCKS/CU in every
// config tested ({512,1024}blk x {16,32,64}KB x {72-100}VGPR all ~19-20%).
// The untested lever is waves-per-block. v12: 512-thread blocks, 8 waves x
// 32 q-rows = 256-row q-tile; per-wave body byte-identical to v8/v11.
// If the 2-block cap holds, waves/CU 8 -> 16 (4/SIMD) and the serial softmax
// chains finally have co-resident waves to hide under.
// Balance: co-resident pair {j, j+256} gets qt=(7-a) and a -> per-CU sum of
// iterations = 36 (constant); longest blocks (qt=7..4) dispatch first.
// Staging: 512 threads stage the 64x64 K and V tiles with 1 async16 each ->
// counted vmcnt(2) steady state. 32 KB LDS dbuf unchanged.
// ---------------------------------------------------------------------------
__global__ __launch_bounds__(512) void attn_kernel(
    const bf16* __restrict__ Q, const bf16* __restrict__ K,
    const bf16* __restrict__ Vt, bf16* __restrict__ O)
{
    __shared__ bf16 k_lds[2][64 * 64];
    __shared__ bf16 v_lds[2][64 * 64];

    const int tid  = threadIdx.x;
    const int wave = tid >> 6;
    const int lane = tid & 63;
    const int l32  = lane & 31;
    const int half = lane >> 5;

    // decode + balance table
    const int j  = blockIdx.x;
    const int bh = j & 63;
    const int h  = bh & 31;
    const int b  = bh >> 5;
    const int a  = j >> 6;                      // 0..7
    const int qt = (a < 4) ? (7 - a) : (a - 4); // first half gets long tiles
    const int hkv = h >> 2;

    const bf16* Qg = Q  + (size_t)(b * H_ + h) * S_ * DH_;
    const bf16* Kg = K  + (size_t)(b * HKV_ + hkv) * S_ * DH_;
    const bf16* Vg = Vt + ((size_t)(b * HKV_ + hkv) * DH_) * S_;

    // staging: 512 threads, 1 row-chunk each (row = tid>>3, chunk = tid&7)
    const int srow   = tid >> 3;                      // 0..63
    const int scolsw = ((tid & 7) ^ (srow & 7)) << 3; // pre-swizzled source col

    const int qb0 = qt * 256 + wave * 32;
    const int qa  = qb0 + l32;
    const int nkt = 4 * qt + 4;

    // Q fragments, B-layout: n=l32 -> q, k = c*16 + half*8 + j -> dh
    bf16x8 qf[4];
    #pragma unroll
    for (int c = 0; c < 4; ++c)
        qf[c] = *(const bf16x8*)(Qg + (size_t)qa * DH_ + c * 16 + half * 8);

    f32x16 o_acc[2];
    #pragma unroll
    for (int dt = 0; dt < 2; ++dt)
        #pragma unroll
        for (int e = 0; e < 16; ++e) o_acc[dt][e] = 0.f;
    float m_i = -1e30f, l_i = 0.f;

    // prefetch tile 0 (1 K-load + 1 V-load per thread; 2/wave in flight)
    async16(Kg + (size_t)srow * DH_ + scolsw, &k_lds[0][tid * 8]);
    async16(Vg + (size_t)srow * S_  + scolsw, &v_lds[0][tid * 8]);

    for (int kt = 0; kt < nkt; ++kt) {
        if (kt + 1 < nkt) {
            bf16* kb = k_lds[(kt + 1) & 1];
            bf16* vb = v_lds[(kt + 1) & 1];
            async16(Kg + (size_t)((kt + 1) * 64 + srow) * DH_ + scolsw,
                    kb + tid * 8);
            async16(Vg + (size_t)srow * S_ + (kt + 1) * 64 + scolsw,
                    vb + tid * 8);
            WAIT_N_BARRIER("s_waitcnt vmcnt(2)");   // tile kt landed; kt+1 in flight
        } else {
            WAIT_N_BARRIER("s_waitcnt vmcnt(0)");
        }

        if (kt * 64 <= qb0 + 31) {
            const bf16* kb = k_lds[kt & 1];
            const bf16* vb = v_lds[kt & 1];
            const bool act1 = (kt * 64 + 32) <= (qb0 + 31);

            // scores tile 0 (kpos kt*64 .. +31); Q pre-scaled -> exp2 dom.
            f32x16 s0, s1;
            {
                bf16x8 kf[4];
                #pragma unroll
                for (int c = 0; c < 4; ++c) {
                    const int col = ((2 * c + half) ^ (l32 & 7)) << 3;
                    kf[c] = *(const bf16x8*)(kb + l32 * 64 + col);
                }
                f32x16 acc;
                #pragma unroll
                for (int e = 0; e < 16; ++e) acc[e] = 0.f;
                __builtin_amdgcn_s_setprio(1);
                #pragma unroll
                for (int c = 0; c < 4; ++c)
                    acc = __builtin_amdgcn_mfma_f32_32x32x16_bf16(kf[c], qf[c], acc, 0, 0, 0);
                __builtin_amdgcn_s_setprio(0);
                s0 = acc;
            }
            if (act1) {
                bf16x8 kf[4];
                #pragma unroll
                for (int c = 0; c < 4; ++c) {
                    const int row = 32 + l32;
                    const int col = ((2 * c + half) ^ (row & 7)) << 3;
                    kf[c] = *(const bf16x8*)(kb + row * 64 + col);
                }
                f32x16 acc;
                #pragma unroll
                for (int e = 0; e < 16; ++e) acc[e] = 0.f;
                __builtin_amdgcn_s_setprio(1);
                #pragma unroll
                for (int c = 0; c < 4; ++c)
                    acc = __builtin_amdgcn_mfma_f32_32x32x16_bf16(kf[c], qf[c], acc, 0, 0, 0);
                __builtin_amdgcn_s_setprio(0);
                s1 = acc;
            }

            // causal mask (partial tiles only; full tiles: no pass)
            if (!((kt * 64 + 31) <= qb0)) {
                const int qrel = qa - kt * 64 - 4 * half;
                #pragma unroll
                for (int e = 0; e < 16; ++e)
                    if (((e & 3) + 8 * (e >> 2)) > qrel) s0[e] = -1e30f;
            }
            if (act1 && !((kt * 64 + 63) <= qb0)) {
                const int qrel = qa - kt * 64 - 32 - 4 * half;
                #pragma unroll
                for (int e = 0; e < 16; ++e)
                    if (((e & 3) + 8 * (e >> 2)) > qrel) s1[e] = -1e30f;
            }

            // stats (per-lane q, combine halves with one xor-32)
            float mx = s0[0];
            #pragma unroll
            for (int e = 1; e < 16; ++e) mx = fmaxf(mx, s0[e]);
            if (act1)
                #pragma unroll
                for (int e = 0; e < 16; ++e) mx = fmaxf(mx, s1[e]);
            mx = fmaxf(mx, __shfl_xor(mx, 32));

            // defer-max: only rescale when tile max grew past m_i + 8
            float al = 1.f;
            if (!__all(mx <= m_i + 8.f)) {
                const float mn = fmaxf(m_i, mx);
                al = exp2f(m_i - mn);
                m_i = mn;
                #pragma unroll
                for (int dt = 0; dt < 2; ++dt)
                    #pragma unroll
                    for (int e = 0; e < 16; ++e) o_acc[dt][e] *= al;
            }

            float sm = 0.f;
            #pragma unroll
            for (int e = 0; e < 16; ++e) {
                const float pp = exp2f(s0[e] - m_i);
                s0[e] = pp; sm += pp;
            }
            if (act1)
                #pragma unroll
                for (int e = 0; e < 16; ++e) {
                    const float pp = exp2f(s1[e] - m_i);
                    s1[e] = pp; sm += pp;
                }
            sm += __shfl_xor(sm, 32);
            l_i = l_i * al + sm;

            // P: C-layout -> B-layout via v_permlane32_swap.
            bf16x8 pf[4];
            {
                uint32_t d0 = pkbf(s0[0],  s0[1]),  d1 = pkbf(s0[2],  s0[3]);
                uint32_t d2 = pkbf(s0[4],  s0[5]),  d3 = pkbf(s0[6],  s0[7]);
                uint32_t d4 = pkbf(s0[8],  s0[9]),  d5 = pkbf(s0[10], s0[11]);
                uint32_t d6 = pkbf(s0[12], s0[13]), d7 = pkbf(s0[14], s0[15]);
                u32x2 r02 = __builtin_amdgcn_permlane32_swap(d0, d2, false, false);
                u32x2 r13 = __builtin_amdgcn_permlane32_swap(d1, d3, false, false);
                u32x2 r46 = __builtin_amdgcn_permlane32_swap(d4, d6, false, false);
                u32x2 r57 = __builtin_amdgcn_permlane32_swap(d5, d7, false, false);
                pf[0] = mk8(r02[0], r13[0], r02[1], r13[1]);
                pf[1] = mk8(r46[0], r57[0], r46[1], r57[1]);
            }
            if (act1) {
                uint32_t d0 = pkbf(s1[0],  s1[1]),  d1 = pkbf(s1[2],  s1[3]);
                uint32_t d2 = pkbf(s1[4],  s1[5]),  d3 = pkbf(s1[6],  s1[7]);
                uint32_t d4 = pkbf(s1[8],  s1[9]),  d5 = pkbf(s1[10], s1[11]);
                uint32_t d6 = pkbf(s1[12], s1[13]), d7 = pkbf(s1[14], s1[15]);
                u32x2 r02 = __builtin_amdgcn_permlane32_swap(d0, d2, false, false);
                u32x2 r13 = __builtin_amdgcn_permlane32_swap(d1, d3, false, false);
                u32x2 r46 = __builtin_amdgcn_permlane32_swap(d4, d6, false, false);
                u32x2 r57 = __builtin_amdgcn_permlane32_swap(d5, d7, false, false);
                pf[2] = mk8(r02[0], r13[0], r02[1], r13[1]);
                pf[3] = mk8(r46[0], r57[0], r46[1], r57[1]);
            }

            // V^T A-frags (loaded late, only needed for PV):
            // vf[dt][c] = V^T[dt*32+l32][c*16+half*8 ..+8]
            bf16x8 vf[2][4];
            #pragma unroll
            for (int dt = 0; dt < 2; ++dt)
                #pragma unroll
                for (int c = 0; c < 4; ++c) {
                    const int row = dt * 32 + l32;
                    const int col = ((2 * c + half) ^ (row & 7)) << 3;
                    vf[dt][c] = *(const bf16x8*)(vb + row * 64 + col);
                }

            // O^T += V^T * P^T over kpos chunks
            const int nc = act1 ? 4 : 2;
            __builtin_amdgcn_s_setprio(1);
            #pragma unroll
            for (int c = 0; c < 4; ++c) {
                if (c >= nc) break;
                #pragma unroll
                for (int dt = 0; dt < 2; ++dt)
                    o_acc[dt] = __builtin_amdgcn_mfma_f32_32x32x16_bf16(
                        vf[dt][c], pf[c], o_acc[dt], 0, 0, 0);
            }
            __builtin_amdgcn_s_setprio(0);
        }
        END_BARRIER();   // all waves done reading buf[kt&1] before kt+2 overwrite
    }

    // epilogue: O^T C-layout -> Ob (b, s, h*64+d); q = l32 same-lane
    const float inv = 1.f / l_i;
    bf16* op = O + ((size_t)(b * S_ + qa) * H_ + h) * DH_;
    #pragma unroll
    for (int dt = 0; dt < 2; ++dt)
        #pragma unroll
        for (int g2 = 0; g2 < 4; ++g2) {
            bf16x4 ov;
            #pragma unroll
            for (int r = 0; r < 4; ++r) ov[r] = (bf16)(o_acc[dt][g2 * 4 + r] * inv);
            *(bf16x4*)(op + dt * 32 + g2 * 8 + half * 4) = ov;
        }
}

// ---------------------------------------------------------------------------
extern "C" void kernel_launch(void* const* d_in, const int* in_sizes, int n_in,
                              void* d_out, int out_size, void* d_ws, size_t ws_size,
                              hipStream_t stream)
{
    const float* X    = (const float*)d_in[0];
    const float* cs   = (const float*)d_in[1];
    const float* sn   = (const float*)d_in[2];
    const float* Wq   = (const float*)d_in[4];
    const float* Wk   = (const float*)d_in[5];
    const float* Wv   = (const float*)d_in[6];
    const float* Wo   = (const float*)d_in[7];
    float* Y          = (float*)d_out;

    bf16* Xb  = (bf16*)d_ws;                       // 8388608
    bf16* Wqb = Xb  + (size_t)8388608;             // 4194304
    bf16* Wkb = Wqb + (size_t)4194304;             // 1048576
    bf16* Wvb = Wkb + (size_t)1048576;             // 1048576
    bf16* Wob = Wvb + (size_t)1048576;             // 4194304
    bf16* Qb  = Wob + (size_t)4194304;             // 8388608
    bf16* Kb  = Qb  + (size_t)8388608;             // 2097152
    bf16* Vtb = Kb  + (size_t)2097152;             // 2097152 (transposed d,s)
    bf16* Ob  = Vtb + (size_t)2097152;             // 8388608

    dim3 blk(256);
    cvt_all_kernel<<<dim3(9216), blk, 0, stream>>>(X, Wq, Wk, Wv, Wo,
                                                   Xb, Wqb, Wkb, Wvb, Wob);
    gemm_qkv_kernel<<<dim3(32, 24), blk, 0, stream>>>(Xb, Wqb, Wkb, Wvb,
                                                      cs, sn, Qb, Kb, Vtb);
    attn_kernel<<<dim3(512), dim3(512), 0, stream>>>(Qb, Kb, Vtb, Ob);
    gemm_out_kernel<<<dim3(32, 16), blk, 0, stream>>>(Ob, Wob, Y);
}

// Round 10
// 352.026 us; speedup vs baseline: 1.0111x; 1.0111x over previous
//
#include <hip/hip_runtime.h>
#include <hip/hip_bf16.h>
#include <cstdint>
#include <cstddef>

// Problem constants
#define B_    2
#define S_    2048
#define HID_  2048
#define H_    32
#define HKV_  8
#define DH_   64
// SCALE * log2(e): scores scaled into exp2 domain
#define SC2_  0.1803368801111244f

typedef __bf16 bf16;
typedef bf16  bf16x2 __attribute__((ext_vector_type(2)));
typedef bf16  bf16x4 __attribute__((ext_vector_type(4)));
typedef bf16  bf16x8 __attribute__((ext_vector_type(8)));
typedef float f32x4  __attribute__((ext_vector_type(4)));
typedef float f32x16 __attribute__((ext_vector_type(16)));
typedef uint32_t u32x2 __attribute__((ext_vector_type(2)));

typedef __attribute__((address_space(3))) uint32_t  lds_u32_t;
typedef __attribute__((address_space(1))) const uint32_t glob_u32_t;

__device__ __forceinline__ void async16(const void* g, void* l) {
    __builtin_amdgcn_global_load_lds((glob_u32_t*)g, (lds_u32_t*)l, 16, 0, 0);
}

__device__ __forceinline__ bf16x8 cvt8(float4 a, float4 b) {
    bf16x8 r;
    r[0] = (bf16)a.x; r[1] = (bf16)a.y; r[2] = (bf16)a.z; r[3] = (bf16)a.w;
    r[4] = (bf16)b.x; r[5] = (bf16)b.y; r[6] = (bf16)b.z; r[7] = (bf16)b.w;
    return r;
}

__device__ __forceinline__ uint32_t pkbf(float a, float b) {
    bf16x2 t; t[0] = (bf16)a; t[1] = (bf16)b;
    return __builtin_bit_cast(uint32_t, t);
}
__device__ __forceinline__ bf16x8 mk8(uint32_t a, uint32_t b, uint32_t c, uint32_t d) {
    union { uint32_t u[4]; bf16x8 v; } t;
    t.u[0] = a; t.u[1] = b; t.u[2] = c; t.u[3] = d;
    return t.v;
}

// ---------------------------------------------------------------------------
// Merged fp32->bf16 convert for all 5 tensors (one launch).
// ---------------------------------------------------------------------------
__global__ __launch_bounds__(256) void cvt_all_kernel(
    const float* __restrict__ X,  const float* __restrict__ Wq,
    const float* __restrict__ Wk, const float* __restrict__ Wv,
    const float* __restrict__ Wo,
    bf16* __restrict__ Xb,  bf16* __restrict__ Wqb, bf16* __restrict__ Wkb,
    bf16* __restrict__ Wvb, bf16* __restrict__ Wob)
{
    const int i = blockIdx.x * 256 + threadIdx.x;
    const float* src; bf16* dst; int off;
    if (i < 1048576)      { src = X;  dst = Xb;  off = i; }
    else if (i < 1572864) { src = Wq; dst = Wqb; off = i - 1048576; }
    else if (i < 1703936) { src = Wk; dst = Wkb; off = i - 1572864; }
    else if (i < 1835008) { src = Wv; dst = Wvb; off = i - 1703936; }
    else                  { src = Wo; dst = Wob; off = i - 1835008; }
    float4 a = ((const float4*)src)[2 * off];
    float4 b = ((const float4*)src)[2 * off + 1];
    ((bf16x8*)dst)[off] = cvt8(a, b);
}

// ---------------------------------------------------------------------------
// Fused QKV projection GEMM — 8-phase 256x256 structure (round 10).
// 512 threads = 8 waves (2M x 4N), per-wave output 128x64. BK=64.
// LDS: 2 dbuf x 2 half x [128x64] x {A,B} = 128 KB; tile u in buf[u&1].
// Per tile: 4 phases {ds_read quadrant frags; MFMA 16; barrier}; tile u+2
// staged into dead slots: B halves at P2 (B(u) last read P1), A halves at
// P3 (A(u) last read P2). ONE counted s_waitcnt vmcnt(8) per tile (tile
// u+1's 8 loads/thread stay in flight across all barriers); vmcnt(0) on
// the last tile. Frag swizzle, staging geometry, C layout, RoPE epilogue
// identical to the HW-verified 128x128 kernel.
// V written TRANSPOSED (b,hkv,d,s); Q pre-scaled by SCALE*log2e.
// ---------------------------------------------------------------------------
__global__ __launch_bounds__(512) void gemm_qkv_kernel(
    const bf16* __restrict__ A,
    const bf16* __restrict__ Wqb, const bf16* __restrict__ Wkb,
    const bf16* __restrict__ Wvb,
    const float* __restrict__ cs, const float* __restrict__ sn,
    bf16* __restrict__ Qo, bf16* __restrict__ Ko, bf16* __restrict__ Vt)
{
    __shared__ bf16 a_lds[2][2][128 * 64];
    __shared__ bf16 b_lds[2][2][128 * 64];

    const int tid  = threadIdx.x;
    const int wave = tid >> 6;
    const int lane = tid & 63;
    const int quad = lane >> 4;
    const int l16  = lane & 15;
    const int wm   = wave >> 2;          // 0..1 : wave's M half (128 rows)
    const int wn   = wave & 3;           // 0..3 : wave's 64-col slice
    const int bh   = wn >> 1;            // B half-array holding this slice

    // XCD swizzle: 192 blocks -> 8 chunks of 24 contiguous tiles
    const int idx = blockIdx.x + 16 * blockIdx.y;      // 0..191
    const int swz = (idx & 7) * 24 + (idx >> 3);
    const int m0  = (swz & 15) * 256;
    const int n0  = (swz >> 4) * 256;

    // staging constants: i in {0,1}; e = element idx in the 128x64 half-tile
    int srow[2], sgcol[2];
    const bf16* browp[2][2];             // [half][i]
    #pragma unroll
    for (int i = 0; i < 2; ++i) {
        const int e = tid * 8 + i * 4096;
        srow[i] = e >> 6;
        const int chunk = (e >> 3) & 7;
        sgcol[i] = (chunk ^ (srow[i] & 7)) << 3;
        #pragma unroll
        for (int h = 0; h < 2; ++h) {
            const int n = n0 + h * 128 + srow[i];
            browp[h][i] = (n < 2048) ? (Wqb + (size_t)n * HID_)
                        : (n < 2560) ? (Wkb + (size_t)(n - 2048) * HID_)
                                     : (Wvb + (size_t)(n - 2560) * HID_);
        }
    }

    // stage helpers: 4 insts each (2 halves x 2 per-thread loads)
    auto stageA = [&](int u) {
        const int k0 = u * 64;
        #pragma unroll
        for (int h = 0; h < 2; ++h)
            #pragma unroll
            for (int i = 0; i < 2; ++i)
                async16(A + (size_t)(m0 + h * 128 + srow[i]) * HID_ + k0 + sgcol[i],
                        &a_lds[u & 1][h][tid * 8 + i * 4096]);
    };
    auto stageB = [&](int u) {
        const int k0 = u * 64;
        #pragma unroll
        for (int h = 0; h < 2; ++h)
            #pragma unroll
            for (int i = 0; i < 2; ++i)
                async16(browp[h][i] + k0 + sgcol[i],
                        &b_lds[u & 1][h][tid * 8 + i * 4096]);
    };

    f32x4 acc[2][2][4][2];               // [mq][nq][mt][nt]
    #pragma unroll
    for (int mq = 0; mq < 2; ++mq)
        #pragma unroll
        for (int nq = 0; nq < 2; ++nq)
            #pragma unroll
            for (int mt = 0; mt < 4; ++mt)
                #pragma unroll
                for (int nt = 0; nt < 2; ++nt)
                    acc[mq][nq][mt][nt] = (f32x4){0.f, 0.f, 0.f, 0.f};

    // prologue: tiles 0 and 1 fully staged (tile0's 8 loads oldest)
    stageA(0); stageB(0);
    stageA(1); stageB(1);

    bf16x8 af[4][2], b0f[2][2], b1f[2][2];

    for (int u = 0; u < 32; ++u) {
        // tile u landed (everything except tile u+1's 8 newest loads)
        if (u + 1 < 32) { asm volatile("s_waitcnt vmcnt(8)" ::: "memory"); }
        else            { asm volatile("s_waitcnt vmcnt(0)" ::: "memory"); }
        __builtin_amdgcn_s_barrier();
        __builtin_amdgcn_sched_barrier(0);

        const bf16* al = &a_lds[u & 1][wm][0];
        const bf16* bl = &b_lds[u & 1][bh][0];

        // ---- P0: read A(mq=0) + B(nq=0); MFMA quadrant (0,0) ----
        #pragma unroll
        for (int mt = 0; mt < 4; ++mt)
            #pragma unroll
            for (int ks = 0; ks < 2; ++ks) {
                const int row = mt * 16 + l16;
                const int c = (ks * 4 + quad) ^ (row & 7);
                af[mt][ks] = *(const bf16x8*)(al + row * 64 + c * 8);
            }
        #pragma unroll
        for (int nt = 0; nt < 2; ++nt)
            #pragma unroll
            for (int ks = 0; ks < 2; ++ks) {
                const int r = (wn & 1) * 64 + nt * 16 + l16;
                const int c = (ks * 4 + quad) ^ (r & 7);
                b0f[nt][ks] = *(const bf16x8*)(bl + r * 64 + c * 8);
            }
        __builtin_amdgcn_s_setprio(1);
        #pragma unroll
        for (int mt = 0; mt < 4; ++mt)
            #pragma unroll
            for (int nt = 0; nt < 2; ++nt)
                #pragma unroll
                for (int ks = 0; ks < 2; ++ks)
                    acc[0][0][mt][nt] = __builtin_amdgcn_mfma_f32_16x16x32_bf16(
                        af[mt][ks], b0f[nt][ks], acc[0][0][mt][nt], 0, 0, 0);
        __builtin_amdgcn_s_setprio(0);
        __builtin_amdgcn_s_barrier();

        // ---- P1: read B(nq=1); MFMA quadrant (0,1) ----
        #pragma unroll
        for (int nt = 0; nt < 2; ++nt)
            #pragma unroll
            for (int ks = 0; ks < 2; ++ks) {
                const int r = (wn & 1) * 64 + 32 + nt * 16 + l16;
                const int c = (ks * 4 + quad) ^ (r & 7);
                b1f[nt][ks] = *(const bf16x8*)(bl + r * 64 + c * 8);
            }
        __builtin_amdgcn_s_setprio(1);
        #pragma unroll
        for (int mt = 0; mt < 4; ++mt)
            #pragma unroll
            for (int nt = 0; nt < 2; ++nt)
                #pragma unroll
                for (int ks = 0; ks < 2; ++ks)
                    acc[0][1][mt][nt] = __builtin_amdgcn_mfma_f32_16x16x32_bf16(
                        af[mt][ks], b1f[nt][ks], acc[0][1][mt][nt], 0, 0, 0);
        __builtin_amdgcn_s_setprio(0);
        __builtin_amdgcn_s_barrier();

        // ---- P2: read A(mq=1); stage B(u+2) into dead B slots; MFMA (1,1) --
        if (u + 2 < 32) stageB(u + 2);
        #pragma unroll
        for (int mt = 0; mt < 4; ++mt)
            #pragma unroll
            for (int ks = 0; ks < 2; ++ks) {
                const int row = 64 + mt * 16 + l16;
                const int c = (ks * 4 + quad) ^ (row & 7);
                af[mt][ks] = *(const bf16x8*)(al + row * 64 + c * 8);
            }
        __builtin_amdgcn_s_setprio(1);
        #pragma unroll
        for (int mt = 0; mt < 4; ++mt)
            #pragma unroll
            for (int nt = 0; nt < 2; ++nt)
                #pragma unroll
                for (int ks = 0; ks < 2; ++ks)
                    acc[1][1][mt][nt] = __builtin_amdgcn_mfma_f32_16x16x32_bf16(
                        af[mt][ks], b1f[nt][ks], acc[1][1][mt][nt], 0, 0, 0);
        __builtin_amdgcn_s_setprio(0);
        __builtin_amdgcn_s_barrier();

        // ---- P3: stage A(u+2) into dead A slots; MFMA (1,0) (b0f in regs) --
        if (u + 2 < 32) stageA(u + 2);
        __builtin_amdgcn_s_setprio(1);
        #pragma unroll
        for (int mt = 0; mt < 4; ++mt)
            #pragma unroll
            for (int nt = 0; nt < 2; ++nt)
                #pragma unroll
                for (int ks = 0; ks < 2; ++ks)
                    acc[1][0][mt][nt] = __builtin_amdgcn_mfma_f32_16x16x32_bf16(
                        af[mt][ks], b0f[nt][ks], acc[1][0][mt][nt], 0, 0, 0);
        __builtin_amdgcn_s_setprio(0);
        // next tile's entry wait+barrier closes this phase
    }

    // epilogue: identical mapping to verified kernel; cols {0,16,32,48}+l16
    const int nw = n0 + wn * 64;
    const int d  = l16;
    #pragma unroll
    for (int mq = 0; mq < 2; ++mq) {
        #pragma unroll
        for (int mt = 0; mt < 4; ++mt) {
            #pragma unroll
            for (int r = 0; r < 4; ++r) {
                const int m  = m0 + wm * 128 + mq * 64 + mt * 16 + quad * 4 + r;
                const int bb = m >> 11;
                const int ss = m & (S_ - 1);
                const float v0 = acc[mq][0][mt][0][r], v1 = acc[mq][0][mt][1][r];
                const float v2 = acc[mq][1][mt][0][r], v3 = acc[mq][1][mt][1][r];
                if (nw < 2048) {
                    const int h = nw >> 6;
                    bf16* dp = Qo + ((size_t)(bb * H_ + h) * S_ + ss) * DH_;
                    const float* cp = cs + ((size_t)bb * S_ + ss) * DH_;
                    const float* sp = sn + ((size_t)bb * S_ + ss) * DH_;
                    dp[ 0 + d] = (bf16)((v0 * cp[ 0 + d] - v2 * sp[ 0 + d]) * SC2_);
                    dp[16 + d] = (bf16)((v1 * cp[16 + d] - v3 * sp[16 + d]) * SC2_);
                    dp[32 + d] = (bf16)((v2 * cp[32 + d] + v0 * sp[32 + d]) * SC2_);
                    dp[48 + d] = (bf16)((v3 * cp[48 + d] + v1 * sp[48 + d]) * SC2_);
                } else if (nw < 2560) {
                    const int h = (nw - 2048) >> 6;
                    bf16* dp = Ko + ((size_t)(bb * HKV_ + h) * S_ + ss) * DH_;
                    const float* cp = cs + ((size_t)bb * S_ + ss) * DH_;
                    const float* sp = sn + ((size_t)bb * S_ + ss) * DH_;
                    dp[ 0 + d] = (bf16)(v0 * cp[ 0 + d] - v2 * sp[ 0 + d]);
                    dp[16 + d] = (bf16)(v1 * cp[16 + d] - v3 * sp[16 + d]);
                    dp[32 + d] = (bf16)(v2 * cp[32 + d] + v0 * sp[32 + d]);
                    dp[48 + d] = (bf16)(v3 * cp[48 + d] + v1 * sp[48 + d]);
                } else {
                    const int h = (nw - 2560) >> 6;
                    bf16* dp = Vt + ((size_t)(bb * HKV_ + h) * DH_) * S_ + ss;
                    dp[(size_t)( 0 + d) * S_] = (bf16)v0;
                    dp[(size_t)(16 + d) * S_] = (bf16)v1;
                    dp[(size_t)(32 + d) * S_] = (bf16)v2;
                    dp[(size_t)(48 + d) * S_] = (bf16)v3;
                }
            }
        }
    }
}

// ---------------------------------------------------------------------------
// Output projection: Y (4096 x 2048 fp32) = Ob (bf16, (b,s,h*d)) * Wob^T.
// 2-phase pipeline + XCD swizzle (512 blocks, 64/XCD) — round-5 verified.
// ---------------------------------------------------------------------------
__global__ __launch_bounds__(256) void gemm_out_kernel(
    const bf16* __restrict__ A, const bf16* __restrict__ Wb,
    float* __restrict__ Y)
{
    __shared__ bf16 a_lds[2][128 * 64];
    __shared__ bf16 b_lds[2][128 * 64];

    const int tid  = threadIdx.x;
    const int wave = tid >> 6;
    const int lane = tid & 63;
    const int quad = lane >> 4;
    const int l16  = lane & 15;
    const int wm   = wave >> 1;
    const int wn   = wave & 1;

    const int idx = blockIdx.x + 32 * blockIdx.y;
    const int swz = (idx & 7) * 64 + (idx >> 3);
    const int m0  = (swz & 31) * 128;
    const int n0  = (swz >> 5) * 128;

    f32x4 acc[4][4];
    #pragma unroll
    for (int mt = 0; mt < 4; ++mt)
        #pragma unroll
        for (int nt = 0; nt < 4; ++nt)
            acc[mt][nt] = (f32x4){0.f, 0.f, 0.f, 0.f};

    int srow[4], sgcol[4];
    #pragma unroll
    for (int i = 0; i < 4; ++i) {
        const int e = tid * 8 + i * 2048;
        srow[i] = e >> 6;
        const int chunk = (e >> 3) & 7;
        sgcol[i] = (chunk ^ (srow[i] & 7)) << 3;
    }

    // prologue: stage K-tile 0 into buffer 0
    #pragma unroll
    for (int i = 0; i < 4; ++i) {
        async16(A + (size_t)(m0 + srow[i]) * HID_ + sgcol[i],
                &a_lds[0][tid * 8 + i * 2048]);
        async16(Wb + (size_t)(n0 + srow[i]) * HID_ + sgcol[i],
                &b_lds[0][tid * 8 + i * 2048]);
    }
    __syncthreads();

    for (int k0 = 0; k0 < HID_; k0 += 64) {
        const int cur = (k0 >> 6) & 1;
        if (k0 + 64 < HID_) {
            #pragma unroll
            for (int i = 0; i < 4; ++i) {
                async16(A + (size_t)(m0 + srow[i]) * HID_ + k0 + 64 + sgcol[i],
                        &a_lds[cur ^ 1][tid * 8 + i * 2048]);
                async16(Wb + (size_t)(n0 + srow[i]) * HID_ + k0 + 64 + sgcol[i],
                        &b_lds[cur ^ 1][tid * 8 + i * 2048]);
            }
        }
        const bf16* al = a_lds[cur];
        const bf16* bl = b_lds[cur];
        #pragma unroll
        for (int ks = 0; ks < 2; ++ks) {
            bf16x8 af[4], bfr[4];
            #pragma unroll
            for (int mt = 0; mt < 4; ++mt) {
                const int row = wm * 64 + mt * 16 + l16;
                const int c = (ks * 4 + quad) ^ (row & 7);
                af[mt] = *(const bf16x8*)(&al[row * 64 + c * 8]);
            }
            #pragma unroll
            for (int nt = 0; nt < 4; ++nt) {
                const int row = wn * 64 + nt * 16 + l16;
                const int c = (ks * 4 + quad) ^ (row & 7);
                bfr[nt] = *(const bf16x8*)(&bl[row * 64 + c * 8]);
            }
            #pragma unroll
            for (int mt = 0; mt < 4; ++mt)
                #pragma unroll
                for (int nt = 0; nt < 4; ++nt)
                    acc[mt][nt] = __builtin_amdgcn_mfma_f32_16x16x32_bf16(
                        af[mt], bfr[nt], acc[mt][nt], 0, 0, 0);
        }
        __syncthreads();
    }

    #pragma unroll
    for (int mt = 0; mt < 4; ++mt)
        #pragma unroll
        for (int nt = 0; nt < 4; ++nt)
            #pragma unroll
            for (int r = 0; r < 4; ++r) {
                const int m = m0 + wm * 64 + mt * 16 + quad * 4 + r;
                const int n = n0 + wn * 64 + nt * 16 + l16;
                Y[(size_t)m * HID_ + n] = acc[mt][nt][r];
            }
}

// ---------------------------------------------------------------------------
// Flash attention v8 (causal, GQA), 32x32x16 MFMA — round-5 best (101.7 us).
// q-tile pair (qt,15-qt), uniform 34 iters, 512 blocks, KVBLK=64, 32 KB LDS
// dbuf, 1 barrier/iter. Micro-opts: Q pre-scaled, partial-tile-only masking,
// defer-max, permlane32_swap P-transpose, late V-frag load, setprio.
// ---------------------------------------------------------------------------
__global__ __launch_bounds__(256) void attn_kernel(
    const bf16* __restrict__ Q, const bf16* __restrict__ K,
    const bf16* __restrict__ Vt, bf16* __restrict__ O)
{
    __shared__ bf16 k_lds[2][64 * 64];
    __shared__ bf16 v_lds[2][64 * 64];

    const int tid  = threadIdx.x;
    const int wave = tid >> 6;
    const int lane = tid & 63;
    const int l32  = lane & 31;
    const int half = lane >> 5;
    const int h  = blockIdx.y;
    const int b  = blockIdx.z;
    const int hkv = h >> 2;

    const bf16* Qg = Q  + (size_t)(b * H_ + h) * S_ * DH_;
    const bf16* Kg = K  + (size_t)(b * HKV_ + hkv) * S_ * DH_;
    const bf16* Vg = Vt + ((size_t)(b * HKV_ + hkv) * DH_) * S_;

    const int srow0  = tid >> 3;
    const int scolsw = ((tid & 7) ^ ((tid >> 3) & 7)) << 3;

    #pragma unroll 1
    for (int ph = 0; ph < 2; ++ph) {
        const int qt  = ph == 0 ? (int)blockIdx.x : (15 - (int)blockIdx.x);
        const int q0  = qt * 128;
        const int qb0 = q0 + wave * 32;
        const int qa  = qb0 + l32;

        // Q fragments, B-layout: n=l32 -> q, k = c*16 + half*8 + j -> dh
        bf16x8 qf[4];
        #pragma unroll
        for (int c = 0; c < 4; ++c)
            qf[c] = *(const bf16x8*)(Qg + (size_t)qa * DH_ + c * 16 + half * 8);

        f32x16 o_acc[2];
        #pragma unroll
        for (int dt = 0; dt < 2; ++dt)
            #pragma unroll
            for (int e = 0; e < 16; ++e) o_acc[dt][e] = 0.f;
        float m_i = -1e30f, l_i = 0.f;

        const int nkt = 2 * qt + 2;

        // prefetch tile 0
        #pragma unroll
        for (int i = 0; i < 2; ++i) {
            const int row = srow0 + i * 32;
            async16(Kg + (size_t)row * DH_ + scolsw, &k_lds[0][tid * 8 + i * 2048]);
            async16(Vg + (size_t)row * S_  + scolsw, &v_lds[0][tid * 8 + i * 2048]);
        }
        __syncthreads();

        for (int kt = 0; kt < nkt; ++kt) {
            if (kt + 1 < nkt) {
                bf16* kb = k_lds[(kt + 1) & 1];
                bf16* vb = v_lds[(kt + 1) & 1];
                #pragma unroll
                for (int i = 0; i < 2; ++i) {
                    const int row = srow0 + i * 32;
                    async16(Kg + (size_t)((kt + 1) * 64 + row) * DH_ + scolsw,
                            kb + tid * 8 + i * 2048);
                    async16(Vg + (size_t)row * S_ + (kt + 1) * 64 + scolsw,
                            vb + tid * 8 + i * 2048);
                }
            }

            if (kt * 64 <= qb0 + 31) {
                const bf16* kb = k_lds[kt & 1];
                const bf16* vb = v_lds[kt & 1];
                const bool act1 = (kt * 64 + 32) <= (qb0 + 31);

                // scores tile 0 (kpos kt*64 .. +31); Q pre-scaled -> exp2 dom.
                f32x16 s0, s1;
                {
                    bf16x8 kf[4];
                    #pragma unroll
                    for (int c = 0; c < 4; ++c) {
                        const int col = ((2 * c + half) ^ (l32 & 7)) << 3;
                        kf[c] = *(const bf16x8*)(kb + l32 * 64 + col);
                    }
                    f32x16 a;
                    #pragma unroll
                    for (int e = 0; e < 16; ++e) a[e] = 0.f;
                    __builtin_amdgcn_s_setprio(1);
                    #pragma unroll
                    for (int c = 0; c < 4; ++c)
                        a = __builtin_amdgcn_mfma_f32_32x32x16_bf16(kf[c], qf[c], a, 0, 0, 0);
                    __builtin_amdgcn_s_setprio(0);
                    s0 = a;
                }
                if (act1) {
                    bf16x8 kf[4];
                    #pragma unroll
                    for (int c = 0; c < 4; ++c) {
                        const int row = 32 + l32;
                        const int col = ((2 * c + half) ^ (row & 7)) << 3;
                        kf[c] = *(const bf16x8*)(kb + row * 64 + col);
                    }
                    f32x16 a;
                    #pragma unroll
                    for (int e = 0; e < 16; ++e) a[e] = 0.f;
                    __builtin_amdgcn_s_setprio(1);
                    #pragma unroll
                    for (int c = 0; c < 4; ++c)
                        a = __builtin_amdgcn_mfma_f32_32x32x16_bf16(kf[c], qf[c], a, 0, 0, 0);
                    __builtin_amdgcn_s_setprio(0);
                    s1 = a;
                }

                // causal mask (partial tiles only; full tiles: no pass)
                if (!((kt * 64 + 31) <= qb0)) {
                    const int qrel = qa - kt * 64 - 4 * half;
                    #pragma unroll
                    for (int e = 0; e < 16; ++e)
                        if (((e & 3) + 8 * (e >> 2)) > qrel) s0[e] = -1e30f;
                }
                if (act1 && !((kt * 64 + 63) <= qb0)) {
                    const int qrel = qa - kt * 64 - 32 - 4 * half;
                    #pragma unroll
                    for (int e = 0; e < 16; ++e)
                        if (((e & 3) + 8 * (e >> 2)) > qrel) s1[e] = -1e30f;
                }

                // stats (per-lane q, combine halves with one xor-32)
                float mx = s0[0];
                #pragma unroll
                for (int e = 1; e < 16; ++e) mx = fmaxf(mx, s0[e]);
                if (act1)
                    #pragma unroll
                    for (int e = 0; e < 16; ++e) mx = fmaxf(mx, s1[e]);
                mx = fmaxf(mx, __shfl_xor(mx, 32));

                // defer-max: only rescale when tile max grew past m_i + 8
                float al = 1.f;
                if (!__all(mx <= m_i + 8.f)) {
                    const float mn = fmaxf(m_i, mx);
                    al = exp2f(m_i - mn);
                    m_i = mn;
                    #pragma unroll
                    for (int dt = 0; dt < 2; ++dt)
                        #pragma unroll
                        for (int e = 0; e < 16; ++e) o_acc[dt][e] *= al;
                }

                float sm = 0.f;
                #pragma unroll
                for (int e = 0; e < 16; ++e) {
                    const float pp = exp2f(s0[e] - m_i);
                    s0[e] = pp; sm += pp;
                }
                if (act1)
                    #pragma unroll
                    for (int e = 0; e < 16; ++e) {
                        const float pp = exp2f(s1[e] - m_i);
                        s1[e] = pp; sm += pp;
                    }
                sm += __shfl_xor(sm, 32);
                l_i = l_i * al + sm;

                // P: C-layout -> B-layout via v_permlane32_swap.
                bf16x8 pf[4];
                {
                    uint32_t d0 = pkbf(s0[0],  s0[1]),  d1 = pkbf(s0[2],  s0[3]);
                    uint32_t d2 = pkbf(s0[4],  s0[5]),  d3 = pkbf(s0[6],  s0[7]);
                    uint32_t d4 = pkbf(s0[8],  s0[9]),  d5 = pkbf(s0[10], s0[11]);
                    uint32_t d6 = pkbf(s0[12], s0[13]), d7 = pkbf(s0[14], s0[15]);
                    u32x2 r02 = __builtin_amdgcn_permlane32_swap(d0, d2, false, false);
                    u32x2 r13 = __builtin_amdgcn_permlane32_swap(d1, d3, false, false);
                    u32x2 r46 = __builtin_amdgcn_permlane32_swap(d4, d6, false, false);
                    u32x2 r57 = __builtin_amdgcn_permlane32_swap(d5, d7, false, false);
                    pf[0] = mk8(r02[0], r13[0], r02[1], r13[1]);
                    pf[1] = mk8(r46[0], r57[0], r46[1], r57[1]);
                }
                if (act1) {
                    uint32_t d0 = pkbf(s1[0],  s1[1]),  d1 = pkbf(s1[2],  s1[3]);
                    uint32_t d2 = pkbf(s1[4],  s1[5]),  d3 = pkbf(s1[6],  s1[7]);
                    uint32_t d4 = pkbf(s1[8],  s1[9]),  d5 = pkbf(s1[10], s1[11]);
                    uint32_t d6 = pkbf(s1[12], s1[13]), d7 = pkbf(s1[14], s1[15]);
                    u32x2 r02 = __builtin_amdgcn_permlane32_swap(d0, d2, false, false);
                    u32x2 r13 = __builtin_amdgcn_permlane32_swap(d1, d3, false, false);
                    u32x2 r46 = __builtin_amdgcn_permlane32_swap(d4, d6, false, false);
                    u32x2 r57 = __builtin_amdgcn_permlane32_swap(d5, d7, false, false);
                    pf[2] = mk8(r02[0], r13[0], r02[1], r13[1]);
                    pf[3] = mk8(r46[0], r57[0], r46[1], r57[1]);
                }

                // V^T A-frags (loaded late, only needed for PV):
                // vf[dt][c] = V^T[dt*32+l32][c*16+half*8 ..+8]
                bf16x8 vf[2][4];
                #pragma unroll
                for (int dt = 0; dt < 2; ++dt)
                    #pragma unroll
                    for (int c = 0; c < 4; ++c) {
                        const int row = dt * 32 + l32;
                        const int col = ((2 * c + half) ^ (row & 7)) << 3;
                        vf[dt][c] = *(const bf16x8*)(vb + row * 64 + col);
                    }

                // O^T += V^T * P^T over kpos chunks
                const int nc = act1 ? 4 : 2;
                __builtin_amdgcn_s_setprio(1);
                #pragma unroll
                for (int c = 0; c < 4; ++c) {
                    if (c >= nc) break;
                    #pragma unroll
                    for (int dt = 0; dt < 2; ++dt)
                        o_acc[dt] = __builtin_amdgcn_mfma_f32_32x32x16_bf16(
                            vf[dt][c], pf[c], o_acc[dt], 0, 0, 0);
                }
                __builtin_amdgcn_s_setprio(0);
            }
            __syncthreads();
        }

        // epilogue: O^T C-layout -> Ob (b, s, h*64+d); q = l32 same-lane
        const float inv = 1.f / l_i;
        bf16* op = O + ((size_t)(b * S_ + qa) * H_ + h) * DH_;
        #pragma unroll
        for (int dt = 0; dt < 2; ++dt)
            #pragma unroll
            for (int g = 0; g < 4; ++g) {
                bf16x4 ov;
                #pragma unroll
                for (int r = 0; r < 4; ++r) ov[r] = (bf16)(o_acc[dt][g * 4 + r] * inv);
                *(bf16x4*)(op + dt * 32 + g * 8 + half * 4) = ov;
            }
        __syncthreads();   // LDS reuse safety before next phase's prefetch
    }
}

// ---------------------------------------------------------------------------
extern "C" void kernel_launch(void* const* d_in, const int* in_sizes, int n_in,
                              void* d_out, int out_size, void* d_ws, size_t ws_size,
                              hipStream_t stream)
{
    const float* X    = (const float*)d_in[0];
    const float* cs   = (const float*)d_in[1];
    const float* sn   = (const float*)d_in[2];
    const float* Wq   = (const float*)d_in[4];
    const float* Wk   = (const float*)d_in[5];
    const float* Wv   = (const float*)d_in[6];
    const float* Wo   = (const float*)d_in[7];
    float* Y          = (float*)d_out;

    bf16* Xb  = (bf16*)d_ws;                       // 8388608
    bf16* Wqb = Xb  + (size_t)8388608;             // 4194304
    bf16* Wkb = Wqb + (size_t)4194304;             // 1048576
    bf16* Wvb = Wkb + (size_t)1048576;             // 1048576
    bf16* Wob = Wvb + (size_t)1048576;             // 4194304
    bf16* Qb  = Wob + (size_t)4194304;             // 8388608
    bf16* Kb  = Qb  + (size_t)8388608;             // 2097152
    bf16* Vtb = Kb  + (size_t)2097152;             // 2097152 (transposed d,s)
    bf16* Ob  = Vtb + (size_t)2097152;             // 8388608

    dim3 blk(256);
    cvt_all_kernel<<<dim3(9216), blk, 0, stream>>>(X, Wq, Wk, Wv, Wo,
                                                   Xb, Wqb, Wkb, Wvb, Wob);
    gemm_qkv_kernel<<<dim3(16, 12), dim3(512), 0, stream>>>(Xb, Wqb, Wkb, Wvb,
                                                            cs, sn, Qb, Kb, Vtb);
    attn_kernel<<<dim3(8, H_, B_), blk, 0, stream>>>(Qb, Kb, Vtb, Ob);
    gemm_out_kernel<<<dim3(32, 16), blk, 0, stream>>>(Ob, Wob, Y);
}

// Round 11
// 344.145 us; speedup vs baseline: 1.0343x; 1.0229x over previous
//
#include <hip/hip_runtime.h>
#include <hip/hip_bf16.h>
#include <cstdint>
#include <cstddef>

// Problem constants
#define B_    2
#define S_    2048
#define HID_  2048
#define H_    32
#define HKV_  8
#define DH_   64
// SCALE * log2(e): scores scaled into exp2 domain
#define SC2_  0.1803368801111244f

typedef __bf16 bf16;
typedef bf16  bf16x2 __attribute__((ext_vector_type(2)));
typedef bf16  bf16x4 __attribute__((ext_vector_type(4)));
typedef bf16  bf16x8 __attribute__((ext_vector_type(8)));
typedef float f32x4  __attribute__((ext_vector_type(4)));
typedef float f32x16 __attribute__((ext_vector_type(16)));
typedef uint32_t u32x2 __attribute__((ext_vector_type(2)));

typedef __attribute__((address_space(3))) uint32_t  lds_u32_t;
typedef __attribute__((address_space(1))) const uint32_t glob_u32_t;

__device__ __forceinline__ void async16(const void* g, void* l) {
    __builtin_amdgcn_global_load_lds((glob_u32_t*)g, (lds_u32_t*)l, 16, 0, 0);
}

__device__ __forceinline__ bf16x8 cvt8(float4 a, float4 b) {
    bf16x8 r;
    r[0] = (bf16)a.x; r[1] = (bf16)a.y; r[2] = (bf16)a.z; r[3] = (bf16)a.w;
    r[4] = (bf16)b.x; r[5] = (bf16)b.y; r[6] = (bf16)b.z; r[7] = (bf16)b.w;
    return r;
}

__device__ __forceinline__ uint32_t pkbf(float a, float b) {
    bf16x2 t; t[0] = (bf16)a; t[1] = (bf16)b;
    return __builtin_bit_cast(uint32_t, t);
}
__device__ __forceinline__ bf16x8 mk8(uint32_t a, uint32_t b, uint32_t c, uint32_t d) {
    union { uint32_t u[4]; bf16x8 v; } t;
    t.u[0] = a; t.u[1] = b; t.u[2] = c; t.u[3] = d;
    return t.v;
}

// depth-4 tree max / depth-5 tree sum (vs 16/32-deep serial chains)
__device__ __forceinline__ float tmax16(const f32x16& v) {
    float a0 = fmaxf(v[0], v[1]),  a1 = fmaxf(v[2], v[3]);
    float a2 = fmaxf(v[4], v[5]),  a3 = fmaxf(v[6], v[7]);
    float a4 = fmaxf(v[8], v[9]),  a5 = fmaxf(v[10], v[11]);
    float a6 = fmaxf(v[12], v[13]), a7 = fmaxf(v[14], v[15]);
    float b0 = fmaxf(a0, a1), b1 = fmaxf(a2, a3);
    float b2 = fmaxf(a4, a5), b3 = fmaxf(a6, a7);
    return fmaxf(fmaxf(b0, b1), fmaxf(b2, b3));
}
__device__ __forceinline__ float tsum16(const f32x16& v) {
    float a0 = v[0] + v[1],  a1 = v[2] + v[3];
    float a2 = v[4] + v[5],  a3 = v[6] + v[7];
    float a4 = v[8] + v[9],  a5 = v[10] + v[11];
    float a6 = v[12] + v[13], a7 = v[14] + v[15];
    float b0 = a0 + a1, b1 = a2 + a3, b2 = a4 + a5, b3 = a6 + a7;
    return (b0 + b1) + (b2 + b3);
}

// ---------------------------------------------------------------------------
// Merged fp32->bf16 convert for all 5 tensors (one launch).
// ---------------------------------------------------------------------------
__global__ __launch_bounds__(256) void cvt_all_kernel(
    const float* __restrict__ X,  const float* __restrict__ Wq,
    const float* __restrict__ Wk, const float* __restrict__ Wv,
    const float* __restrict__ Wo,
    bf16* __restrict__ Xb,  bf16* __restrict__ Wqb, bf16* __restrict__ Wkb,
    bf16* __restrict__ Wvb, bf16* __restrict__ Wob)
{
    const int i = blockIdx.x * 256 + threadIdx.x;
    const float* src; bf16* dst; int off;
    if (i < 1048576)      { src = X;  dst = Xb;  off = i; }
    else if (i < 1572864) { src = Wq; dst = Wqb; off = i - 1048576; }
    else if (i < 1703936) { src = Wk; dst = Wkb; off = i - 1572864; }
    else if (i < 1835008) { src = Wv; dst = Wvb; off = i - 1703936; }
    else                  { src = Wo; dst = Wob; off = i - 1835008; }
    float4 a = ((const float4*)src)[2 * off];
    float4 b = ((const float4*)src)[2 * off + 1];
    ((bf16x8*)dst)[off] = cvt8(a, b);
}

// ---------------------------------------------------------------------------
// Fused QKV projection GEMM (round-5 verified config). V written TRANSPOSED.
// Q pre-scaled by SCALE*log2e. 2-phase pipeline (dbuf LDS, STAGE(t+1) before
// compute(t), 1 barrier/step) + bijective XCD swizzle.
// ---------------------------------------------------------------------------
__global__ __launch_bounds__(256) void gemm_qkv_kernel(
    const bf16* __restrict__ A,
    const bf16* __restrict__ Wqb, const bf16* __restrict__ Wkb,
    const bf16* __restrict__ Wvb,
    const float* __restrict__ cs, const float* __restrict__ sn,
    bf16* __restrict__ Qo, bf16* __restrict__ Ko, bf16* __restrict__ Vt)
{
    __shared__ bf16 a_lds[2][128 * 64];
    __shared__ bf16 b_lds[2][128 * 64];

    const int tid  = threadIdx.x;
    const int wave = tid >> 6;
    const int lane = tid & 63;
    const int quad = lane >> 4;
    const int l16  = lane & 15;
    const int wm   = wave >> 1;
    const int wn   = wave & 1;

    // XCD-aware swizzle: 768 blocks -> 8 chunks of 96 contiguous tiles
    const int idx = blockIdx.x + 32 * blockIdx.y;
    const int swz = (idx & 7) * 96 + (idx >> 3);
    const int m0  = (swz & 31) * 128;
    const int n0  = (swz >> 5) * 128;

    f32x4 acc[4][4];
    #pragma unroll
    for (int mt = 0; mt < 4; ++mt)
        #pragma unroll
        for (int nt = 0; nt < 4; ++nt)
            acc[mt][nt] = (f32x4){0.f, 0.f, 0.f, 0.f};

    int srow[4], sgcol[4];
    const bf16* browp[4];
    #pragma unroll
    for (int i = 0; i < 4; ++i) {
        const int e = tid * 8 + i * 2048;
        srow[i] = e >> 6;
        const int chunk = (e >> 3) & 7;
        sgcol[i] = (chunk ^ (srow[i] & 7)) << 3;
        const int n = n0 + srow[i];
        browp[i] = (n < 2048) ? (Wqb + (size_t)n * HID_)
                 : (n < 2560) ? (Wkb + (size_t)(n - 2048) * HID_)
                              : (Wvb + (size_t)(n - 2560) * HID_);
    }

    // prologue: stage K-tile 0 into buffer 0
    #pragma unroll
    for (int i = 0; i < 4; ++i) {
        async16(A + (size_t)(m0 + srow[i]) * HID_ + sgcol[i],
                &a_lds[0][tid * 8 + i * 2048]);
        async16(browp[i] + sgcol[i],
                &b_lds[0][tid * 8 + i * 2048]);
    }
    __syncthreads();

    for (int k0 = 0; k0 < HID_; k0 += 64) {
        const int cur = (k0 >> 6) & 1;
        if (k0 + 64 < HID_) {
            #pragma unroll
            for (int i = 0; i < 4; ++i) {
                async16(A + (size_t)(m0 + srow[i]) * HID_ + k0 + 64 + sgcol[i],
                        &a_lds[cur ^ 1][tid * 8 + i * 2048]);
                async16(browp[i] + k0 + 64 + sgcol[i],
                        &b_lds[cur ^ 1][tid * 8 + i * 2048]);
            }
        }
        const bf16* al = a_lds[cur];
        const bf16* bl = b_lds[cur];
        #pragma unroll
        for (int ks = 0; ks < 2; ++ks) {
            bf16x8 af[4], bfr[4];
            #pragma unroll
            for (int mt = 0; mt < 4; ++mt) {
                const int row = wm * 64 + mt * 16 + l16;
                const int c = (ks * 4 + quad) ^ (row & 7);
                af[mt] = *(const bf16x8*)(&al[row * 64 + c * 8]);
            }
            #pragma unroll
            for (int nt = 0; nt < 4; ++nt) {
                const int row = wn * 64 + nt * 16 + l16;
                const int c = (ks * 4 + quad) ^ (row & 7);
                bfr[nt] = *(const bf16x8*)(&bl[row * 64 + c * 8]);
            }
            #pragma unroll
            for (int mt = 0; mt < 4; ++mt)
                #pragma unroll
                for (int nt = 0; nt < 4; ++nt)
                    acc[mt][nt] = __builtin_amdgcn_mfma_f32_16x16x32_bf16(
                        af[mt], bfr[nt], acc[mt][nt], 0, 0, 0);
        }
        __syncthreads();   // drains vmcnt(0) (next tile staged) + barrier
    }

    const int nw = n0 + wn * 64;
    const int d  = l16;
    #pragma unroll
    for (int mt = 0; mt < 4; ++mt) {
        #pragma unroll
        for (int r = 0; r < 4; ++r) {
            const int m  = m0 + wm * 64 + mt * 16 + quad * 4 + r;
            const int bb = m >> 11;
            const int ss = m & (S_ - 1);
            const float v0 = acc[mt][0][r], v1 = acc[mt][1][r];
            const float v2 = acc[mt][2][r], v3 = acc[mt][3][r];
            if (nw < 2048) {
                const int h = nw >> 6;
                bf16* dp = Qo + ((size_t)(bb * H_ + h) * S_ + ss) * DH_;
                const float* cp = cs + ((size_t)bb * S_ + ss) * DH_;
                const float* sp = sn + ((size_t)bb * S_ + ss) * DH_;
                dp[ 0 + d] = (bf16)((v0 * cp[ 0 + d] - v2 * sp[ 0 + d]) * SC2_);
                dp[16 + d] = (bf16)((v1 * cp[16 + d] - v3 * sp[16 + d]) * SC2_);
                dp[32 + d] = (bf16)((v2 * cp[32 + d] + v0 * sp[32 + d]) * SC2_);
                dp[48 + d] = (bf16)((v3 * cp[48 + d] + v1 * sp[48 + d]) * SC2_);
            } else if (nw < 2560) {
                const int h = (nw - 2048) >> 6;
                bf16* dp = Ko + ((size_t)(bb * HKV_ + h) * S_ + ss) * DH_;
                const float* cp = cs + ((size_t)bb * S_ + ss) * DH_;
                const float* sp = sn + ((size_t)bb * S_ + ss) * DH_;
                dp[ 0 + d] = (bf16)(v0 * cp[ 0 + d] - v2 * sp[ 0 + d]);
                dp[16 + d] = (bf16)(v1 * cp[16 + d] - v3 * sp[16 + d]);
                dp[32 + d] = (bf16)(v2 * cp[32 + d] + v0 * sp[32 + d]);
                dp[48 + d] = (bf16)(v3 * cp[48 + d] + v1 * sp[48 + d]);
            } else {
                const int h = (nw - 2560) >> 6;
                bf16* dp = Vt + ((size_t)(bb * HKV_ + h) * DH_) * S_ + ss;
                dp[(size_t)( 0 + d) * S_] = (bf16)v0;
                dp[(size_t)(16 + d) * S_] = (bf16)v1;
                dp[(size_t)(32 + d) * S_] = (bf16)v2;
                dp[(size_t)(48 + d) * S_] = (bf16)v3;
            }
        }
    }
}

// ---------------------------------------------------------------------------
// Output projection: Y (4096 x 2048 fp32) = Ob (bf16, (b,s,h*d)) * Wob^T.
// 2-phase pipeline + XCD swizzle (512 blocks, 64/XCD) — round-5 verified.
// ---------------------------------------------------------------------------
__global__ __launch_bounds__(256) void gemm_out_kernel(
    const bf16* __restrict__ A, const bf16* __restrict__ Wb,
    float* __restrict__ Y)
{
    __shared__ bf16 a_lds[2][128 * 64];
    __shared__ bf16 b_lds[2][128 * 64];

    const int tid  = threadIdx.x;
    const int wave = tid >> 6;
    const int lane = tid & 63;
    const int quad = lane >> 4;
    const int l16  = lane & 15;
    const int wm   = wave >> 1;
    const int wn   = wave & 1;

    const int idx = blockIdx.x + 32 * blockIdx.y;
    const int swz = (idx & 7) * 64 + (idx >> 3);
    const int m0  = (swz & 31) * 128;
    const int n0  = (swz >> 5) * 128;

    f32x4 acc[4][4];
    #pragma unroll
    for (int mt = 0; mt < 4; ++mt)
        #pragma unroll
        for (int nt = 0; nt < 4; ++nt)
            acc[mt][nt] = (f32x4){0.f, 0.f, 0.f, 0.f};

    int srow[4], sgcol[4];
    #pragma unroll
    for (int i = 0; i < 4; ++i) {
        const int e = tid * 8 + i * 2048;
        srow[i] = e >> 6;
        const int chunk = (e >> 3) & 7;
        sgcol[i] = (chunk ^ (srow[i] & 7)) << 3;
    }

    // prologue: stage K-tile 0 into buffer 0
    #pragma unroll
    for (int i = 0; i < 4; ++i) {
        async16(A + (size_t)(m0 + srow[i]) * HID_ + sgcol[i],
                &a_lds[0][tid * 8 + i * 2048]);
        async16(Wb + (size_t)(n0 + srow[i]) * HID_ + sgcol[i],
                &b_lds[0][tid * 8 + i * 2048]);
    }
    __syncthreads();

    for (int k0 = 0; k0 < HID_; k0 += 64) {
        const int cur = (k0 >> 6) & 1;
        if (k0 + 64 < HID_) {
            #pragma unroll
            for (int i = 0; i < 4; ++i) {
                async16(A + (size_t)(m0 + srow[i]) * HID_ + k0 + 64 + sgcol[i],
                        &a_lds[cur ^ 1][tid * 8 + i * 2048]);
                async16(Wb + (size_t)(n0 + srow[i]) * HID_ + k0 + 64 + sgcol[i],
                        &b_lds[cur ^ 1][tid * 8 + i * 2048]);
            }
        }
        const bf16* al = a_lds[cur];
        const bf16* bl = b_lds[cur];
        #pragma unroll
        for (int ks = 0; ks < 2; ++ks) {
            bf16x8 af[4], bfr[4];
            #pragma unroll
            for (int mt = 0; mt < 4; ++mt) {
                const int row = wm * 64 + mt * 16 + l16;
                const int c = (ks * 4 + quad) ^ (row & 7);
                af[mt] = *(const bf16x8*)(&al[row * 64 + c * 8]);
            }
            #pragma unroll
            for (int nt = 0; nt < 4; ++nt) {
                const int row = wn * 64 + nt * 16 + l16;
                const int c = (ks * 4 + quad) ^ (row & 7);
                bfr[nt] = *(const bf16x8*)(&bl[row * 64 + c * 8]);
            }
            #pragma unroll
            for (int mt = 0; mt < 4; ++mt)
                #pragma unroll
                for (int nt = 0; nt < 4; ++nt)
                    acc[mt][nt] = __builtin_amdgcn_mfma_f32_16x16x32_bf16(
                        af[mt], bfr[nt], acc[mt][nt], 0, 0, 0);
        }
        __syncthreads();
    }

    #pragma unroll
    for (int mt = 0; mt < 4; ++mt)
        #pragma unroll
        for (int nt = 0; nt < 4; ++nt)
            #pragma unroll
            for (int r = 0; r < 4; ++r) {
                const int m = m0 + wm * 64 + mt * 16 + quad * 4 + r;
                const int n = n0 + wn * 64 + nt * 16 + l16;
                Y[(size_t)m * HID_ + n] = acc[mt][nt][r];
            }
}

// ---------------------------------------------------------------------------
// Flash attention v13 (causal, GQA), 32x32x16 MFMA — DOUBLE-WIDTH ITERATIONS.
// R10 analysis: attn is dependency-latency-bound (~70% dual-pipe idle at 2
// blocks/CU, every occupancy lever nulled). v13 attacks the per-iteration
// critical path instead: TWO 64-kpos tiles per barrier window (4-slot LDS,
// 64 KB — residency unchanged, 2 blocks/CU was the cap). Barriers + vmcnt
// waits per kpos halved; tile 2t+1's score MFMAs are independent of tile
// 2t's softmax -> intra-wave MFMA/VALU overlap. fmax/sum chains tree-reduced
// (16/32-deep -> 4/5-deep). Per-subtile body = verified v8 code (lambda).
// Shell: q-tile pair (qt,15-qt), uniform work, 512 blocks.
// ---------------------------------------------------------------------------
__global__ __launch_bounds__(256) void attn_kernel(
    const bf16* __restrict__ Q, const bf16* __restrict__ K,
    const bf16* __restrict__ Vt, bf16* __restrict__ O)
{
    __shared__ bf16 k_lds[4][64 * 64];
    __shared__ bf16 v_lds[4][64 * 64];

    const int tid  = threadIdx.x;
    const int wave = tid >> 6;
    const int lane = tid & 63;
    const int l32  = lane & 31;
    const int half = lane >> 5;
    const int h  = blockIdx.y;
    const int b  = blockIdx.z;
    const int hkv = h >> 2;

    const bf16* Qg = Q  + (size_t)(b * H_ + h) * S_ * DH_;
    const bf16* Kg = K  + (size_t)(b * HKV_ + hkv) * S_ * DH_;
    const bf16* Vg = Vt + ((size_t)(b * HKV_ + hkv) * DH_) * S_;

    const int srow0  = tid >> 3;
    const int scolsw = ((tid & 7) ^ ((tid >> 3) & 7)) << 3;

    #pragma unroll 1
    for (int ph = 0; ph < 2; ++ph) {
        const int qt  = ph == 0 ? (int)blockIdx.x : (15 - (int)blockIdx.x);
        const int qb0 = qt * 128 + wave * 32;
        const int qa  = qb0 + l32;
        const int nit = qt + 1;              // (2qt+2)/2 double-width iters

        // Q fragments, B-layout: n=l32 -> q, k = c*16 + half*8 + j -> dh
        bf16x8 qf[4];
        #pragma unroll
        for (int c = 0; c < 4; ++c)
            qf[c] = *(const bf16x8*)(Qg + (size_t)qa * DH_ + c * 16 + half * 8);

        f32x16 o_acc[2];
        #pragma unroll
        for (int dt = 0; dt < 2; ++dt)
            #pragma unroll
            for (int e = 0; e < 16; ++e) o_acc[dt][e] = 0.f;
        float m_i = -1e30f, l_i = 0.f;

        // per-subtile body (verified v8 code + tree-reduced stats)
        auto process = [&](int kt) {
            if (kt * 64 > qb0 + 31) return;
            const bf16* kb = &k_lds[kt & 3][0];
            const bf16* vb = &v_lds[kt & 3][0];
            const bool act1 = (kt * 64 + 32) <= (qb0 + 31);

            // scores tile 0 (kpos kt*64 .. +31); Q pre-scaled -> exp2 domain
            f32x16 s0, s1;
            {
                bf16x8 kf[4];
                #pragma unroll
                for (int c = 0; c < 4; ++c) {
                    const int col = ((2 * c + half) ^ (l32 & 7)) << 3;
                    kf[c] = *(const bf16x8*)(kb + l32 * 64 + col);
                }
                f32x16 a;
                #pragma unroll
                for (int e = 0; e < 16; ++e) a[e] = 0.f;
                __builtin_amdgcn_s_setprio(1);
                #pragma unroll
                for (int c = 0; c < 4; ++c)
                    a = __builtin_amdgcn_mfma_f32_32x32x16_bf16(kf[c], qf[c], a, 0, 0, 0);
                __builtin_amdgcn_s_setprio(0);
                s0 = a;
            }
            if (act1) {
                bf16x8 kf[4];
                #pragma unroll
                for (int c = 0; c < 4; ++c) {
                    const int row = 32 + l32;
                    const int col = ((2 * c + half) ^ (row & 7)) << 3;
                    kf[c] = *(const bf16x8*)(kb + row * 64 + col);
                }
                f32x16 a;
                #pragma unroll
                for (int e = 0; e < 16; ++e) a[e] = 0.f;
                __builtin_amdgcn_s_setprio(1);
                #pragma unroll
                for (int c = 0; c < 4; ++c)
                    a = __builtin_amdgcn_mfma_f32_32x32x16_bf16(kf[c], qf[c], a, 0, 0, 0);
                __builtin_amdgcn_s_setprio(0);
                s1 = a;
            }

            // causal mask (partial tiles only; full tiles: no pass)
            if (!((kt * 64 + 31) <= qb0)) {
                const int qrel = qa - kt * 64 - 4 * half;
                #pragma unroll
                for (int e = 0; e < 16; ++e)
                    if (((e & 3) + 8 * (e >> 2)) > qrel) s0[e] = -1e30f;
            }
            if (act1 && !((kt * 64 + 63) <= qb0)) {
                const int qrel = qa - kt * 64 - 32 - 4 * half;
                #pragma unroll
                for (int e = 0; e < 16; ++e)
                    if (((e & 3) + 8 * (e >> 2)) > qrel) s1[e] = -1e30f;
            }

            // stats: tree max (depth 4), halves combined with one xor-32
            float mx = tmax16(s0);
            if (act1) mx = fmaxf(mx, tmax16(s1));
            mx = fmaxf(mx, __shfl_xor(mx, 32));

            // defer-max: only rescale when tile max grew past m_i + 8
            float al = 1.f;
            if (!__all(mx <= m_i + 8.f)) {
                const float mn = fmaxf(m_i, mx);
                al = exp2f(m_i - mn);
                m_i = mn;
                #pragma unroll
                for (int dt = 0; dt < 2; ++dt)
                    #pragma unroll
                    for (int e = 0; e < 16; ++e) o_acc[dt][e] *= al;
            }

            // exp (independent ops) then tree sum (depth 5)
            #pragma unroll
            for (int e = 0; e < 16; ++e) s0[e] = exp2f(s0[e] - m_i);
            float sm = tsum16(s0);
            if (act1) {
                #pragma unroll
                for (int e = 0; e < 16; ++e) s1[e] = exp2f(s1[e] - m_i);
                sm += tsum16(s1);
            }
            sm += __shfl_xor(sm, 32);
            l_i = l_i * al + sm;

            // P: C-layout -> B-layout via v_permlane32_swap.
            bf16x8 pf[4];
            {
                uint32_t d0 = pkbf(s0[0],  s0[1]),  d1 = pkbf(s0[2],  s0[3]);
                uint32_t d2 = pkbf(s0[4],  s0[5]),  d3 = pkbf(s0[6],  s0[7]);
                uint32_t d4 = pkbf(s0[8],  s0[9]),  d5 = pkbf(s0[10], s0[11]);
                uint32_t d6 = pkbf(s0[12], s0[13]), d7 = pkbf(s0[14], s0[15]);
                u32x2 r02 = __builtin_amdgcn_permlane32_swap(d0, d2, false, false);
                u32x2 r13 = __builtin_amdgcn_permlane32_swap(d1, d3, false, false);
                u32x2 r46 = __builtin_amdgcn_permlane32_swap(d4, d6, false, false);
                u32x2 r57 = __builtin_amdgcn_permlane32_swap(d5, d7, false, false);
                pf[0] = mk8(r02[0], r13[0], r02[1], r13[1]);
                pf[1] = mk8(r46[0], r57[0], r46[1], r57[1]);
            }
            if (act1) {
                uint32_t d0 = pkbf(s1[0],  s1[1]),  d1 = pkbf(s1[2],  s1[3]);
                uint32_t d2 = pkbf(s1[4],  s1[5]),  d3 = pkbf(s1[6],  s1[7]);
                uint32_t d4 = pkbf(s1[8],  s1[9]),  d5 = pkbf(s1[10], s1[11]);
                uint32_t d6 = pkbf(s1[12], s1[13]), d7 = pkbf(s1[14], s1[15]);
                u32x2 r02 = __builtin_amdgcn_permlane32_swap(d0, d2, false, false);
                u32x2 r13 = __builtin_amdgcn_permlane32_swap(d1, d3, false, false);
                u32x2 r46 = __builtin_amdgcn_permlane32_swap(d4, d6, false, false);
                u32x2 r57 = __builtin_amdgcn_permlane32_swap(d5, d7, false, false);
                pf[2] = mk8(r02[0], r13[0], r02[1], r13[1]);
                pf[3] = mk8(r46[0], r57[0], r46[1], r57[1]);
            }

            // V^T A-frags (late load, PV only): vf[dt][c]
            bf16x8 vf[2][4];
            #pragma unroll
            for (int dt = 0; dt < 2; ++dt)
                #pragma unroll
                for (int c = 0; c < 4; ++c) {
                    const int row = dt * 32 + l32;
                    const int col = ((2 * c + half) ^ (row & 7)) << 3;
                    vf[dt][c] = *(const bf16x8*)(vb + row * 64 + col);
                }

            // O^T += V^T * P^T over kpos chunks
            const int nc = act1 ? 4 : 2;
            __builtin_amdgcn_s_setprio(1);
            #pragma unroll
            for (int c = 0; c < 4; ++c) {
                if (c >= nc) break;
                #pragma unroll
                for (int dt = 0; dt < 2; ++dt)
                    o_acc[dt] = __builtin_amdgcn_mfma_f32_32x32x16_bf16(
                        vf[dt][c], pf[c], o_acc[dt], 0, 0, 0);
            }
            __builtin_amdgcn_s_setprio(0);
        };

        // prologue: stage tiles 0,1 into slots 0,1 (8 loads/wave)
        #pragma unroll
        for (int t = 0; t < 2; ++t)
            #pragma unroll
            for (int i = 0; i < 2; ++i) {
                const int row = srow0 + i * 32;
                async16(Kg + (size_t)(t * 64 + row) * DH_ + scolsw,
                        &k_lds[t][tid * 8 + i * 2048]);
                async16(Vg + (size_t)row * S_ + t * 64 + scolsw,
                        &v_lds[t][tid * 8 + i * 2048]);
            }

        for (int it = 0; it < nit; ++it) {
            if (it + 1 < nit) {
                #pragma unroll
                for (int t = 0; t < 2; ++t) {
                    const int kt = 2 * it + 2 + t;
                    bf16* kb = &k_lds[kt & 3][0];
                    bf16* vb = &v_lds[kt & 3][0];
                    #pragma unroll
                    for (int i = 0; i < 2; ++i) {
                        const int row = srow0 + i * 32;
                        async16(Kg + (size_t)(kt * 64 + row) * DH_ + scolsw,
                                kb + tid * 8 + i * 2048);
                        async16(Vg + (size_t)row * S_ + kt * 64 + scolsw,
                                vb + tid * 8 + i * 2048);
                    }
                }
                asm volatile("s_waitcnt vmcnt(8)" ::: "memory");  // tiles 2it,2it+1 landed
            } else {
                asm volatile("s_waitcnt vmcnt(0)" ::: "memory");
            }
            __builtin_amdgcn_s_barrier();
            __builtin_amdgcn_sched_barrier(0);

            process(2 * it);
            process(2 * it + 1);

            __builtin_amdgcn_sched_barrier(0);
            __builtin_amdgcn_s_barrier();   // protect slots before overwrite
        }

        // epilogue: O^T C-layout -> Ob (b, s, h*64+d); q = l32 same-lane
        const float inv = 1.f / l_i;
        bf16* op = O + ((size_t)(b * S_ + qa) * H_ + h) * DH_;
        #pragma unroll
        for (int dt = 0; dt < 2; ++dt)
            #pragma unroll
            for (int g = 0; g < 4; ++g) {
                bf16x4 ov;
                #pragma unroll
                for (int r = 0; r < 4; ++r) ov[r] = (bf16)(o_acc[dt][g * 4 + r] * inv);
                *(bf16x4*)(op + dt * 32 + g * 8 + half * 4) = ov;
            }
        __syncthreads();   // LDS reuse safety before next phase's prologue
    }
}

// ---------------------------------------------------------------------------
extern "C" void kernel_launch(void* const* d_in, const int* in_sizes, int n_in,
                              void* d_out, int out_size, void* d_ws, size_t ws_size,
                              hipStream_t stream)
{
    const float* X    = (const float*)d_in[0];
    const float* cs   = (const float*)d_in[1];
    const float* sn   = (const float*)d_in[2];
    const float* Wq   = (const float*)d_in[4];
    const float* Wk   = (const float*)d_in[5];
    const float* Wv   = (const float*)d_in[6];
    const float* Wo   = (const float*)d_in[7];
    float* Y          = (float*)d_out;

    bf16* Xb  = (bf16*)d_ws;                       // 8388608
    bf16* Wqb = Xb  + (size_t)8388608;             // 4194304
    bf16* Wkb = Wqb + (size_t)4194304;             // 1048576
    bf16* Wvb = Wkb + (size_t)1048576;             // 1048576
    bf16* Wob = Wvb + (size_t)1048576;             // 4194304
    bf16* Qb  = Wob + (size_t)4194304;             // 8388608
    bf16* Kb  = Qb  + (size_t)8388608;             // 2097152
    bf16* Vtb = Kb  + (size_t)2097152;             // 2097152 (transposed d,s)
    bf16* Ob  = Vtb + (size_t)2097152;             // 8388608

    dim3 blk(256);
    cvt_all_kernel<<<dim3(9216), blk, 0, stream>>>(X, Wq, Wk, Wv, Wo,
                                                   Xb, Wqb, Wkb, Wvb, Wob);
    gemm_qkv_kernel<<<dim3(32, 24), blk, 0, stream>>>(Xb, Wqb, Wkb, Wvb,
                                                      cs, sn, Qb, Kb, Vtb);
    attn_kernel<<<dim3(8, H_, B_), blk, 0, stream>>>(Qb, Kb, Vtb, Ob);
    gemm_out_kernel<<<dim3(32, 16), blk, 0, stream>>>(Ob, Wob, Y);
}